// Round 2
// baseline (103.187 us; speedup 1.0000x reference)
//
#include <hip/hip_runtime.h>

#define NRAYS 8192
#define NS    256
#define HID   64
#define NPAIR 32     // hidden-unit pairs
#define RPB   8      // rays per block: 4 waves x 2 rays each

typedef _Float16 f16x2 __attribute__((ext_vector_type(2)));
typedef _Float16 f16x8 __attribute__((ext_vector_type(8)));
typedef float    f32x4 __attribute__((ext_vector_type(4)));

static __device__ __forceinline__ f16x2 mk2(float a, float b) {
    f16x2 v; v.x = (_Float16)a; v.y = (_Float16)b; return v;
}

struct __align__(8) AB2 { f16x2 A, B; };   // hv(h,t) = relu(A + t*B), 2 units packed
union AFrag { f16x8 v; f16x2 h[4]; };      // MFMA A-operand built from 4 pk results

__global__ __launch_bounds__(256, 4) void vr_kernel(
    const float* __restrict__ ray_start,
    const float* __restrict__ ray_dir,
    const float* __restrict__ sampled_depth,
    const float* __restrict__ sampled_dists,
    const int*   __restrict__ sampled_idx,
    const float* __restrict__ W1,
    const float* __restrict__ b1,
    const float* __restrict__ w_sigma,
    const float* __restrict__ W_rgb,
    const float* __restrict__ W_dir,
    const float* __restrict__ b_rgb,
    float* __restrict__ out)
{
    // All LDS regions are produced and consumed by the SAME wave (wave w owns
    // rays 2w and 2w+1; staging threads t have t>>5 == 2w or 2w+1). DS ops from
    // one wave execute in order -> no __syncthreads anywhere.
    __shared__ AB2   sAB[RPB][NPAIR];                 // 2 KB
    __shared__ f16x2 sDep[RPB][NS];                   // 8 KB   (t,t) f16 pairs
    __shared__ __align__(16) float sOut[4][4][264];   // 16.9 KB, per-wave transpose buf (pad 264)

    const int t = threadIdx.x;

    {   // stage sAB: 256 threads = 8 rays x 32 pairs
        const int rr  = t >> 5;
        const int k   = t & (NPAIR - 1);
        const int ray = blockIdx.x * RPB + rr;
        const float ox = ray_start[ray*3+0], oy = ray_start[ray*3+1], oz = ray_start[ray*3+2];
        const float dx = ray_dir[ray*3+0],  dy = ray_dir[ray*3+1],  dz = ray_dir[ray*3+2];
        const int h0 = 2*k, h1 = 2*k + 1;
        const float u0 = W1[h0], u1 = W1[HID + h0], u2 = W1[2*HID + h0];
        const float v0 = W1[h1], v1 = W1[HID + h1], v2 = W1[2*HID + h1];
        const float A0 = fmaf(u0, ox, fmaf(u1, oy, fmaf(u2, oz, b1[h0])));
        const float B0 = fmaf(u0, dx, fmaf(u1, dy, u2 * dz));
        const float A1 = fmaf(v0, ox, fmaf(v1, oy, fmaf(v2, oz, b1[h1])));
        const float B1 = fmaf(v0, dx, fmaf(v1, dy, v2 * dz));
        AB2 e; e.A = mk2(A0, A1); e.B = mk2(B0, B1);
        sAB[rr][k] = e;
    }
    {   // stage sDep: depth as broadcast f16 pairs, 8 samples/thread
        const int rr  = t >> 5;
        const int i   = t & 31;
        const int ray = blockIdx.x * RPB + rr;
        const size_t base = (size_t)ray * NS + (size_t)i * 8;
        const float4 d0 = ((const float4*)(sampled_depth + base))[0];
        const float4 d1 = ((const float4*)(sampled_depth + base))[1];
        f16x2* dst = &sDep[rr][i*8];
        dst[0] = mk2(d0.x, d0.x); dst[1] = mk2(d0.y, d0.y);
        dst[2] = mk2(d0.z, d0.z); dst[3] = mk2(d0.w, d0.w);
        dst[4] = mk2(d1.x, d1.x); dst[5] = mk2(d1.y, d1.y);
        dst[6] = mk2(d1.z, d1.z); dst[7] = mk2(d1.w, d1.w);
    }

    const int lane = t & 63;
    const int wave = t >> 6;
    const int col  = lane & 15;   // A-row (sample-in-block) == B/D col (output)
    const int g    = lane >> 4;   // k-chunk group

    // B fragments, pinned in VGPRs for the whole kernel.
    // B[k][col]: col0 = w_sigma, col1..3 = W_rgb[:,col-1], col>=4 zero.
    // lane holds k = g*8+e (bf0) and 32+g*8+e (bf1).
    f16x8 bf0, bf1;
#pragma unroll
    for (int e = 0; e < 8; ++e) {
        const int u0 = g*8 + e, u1 = 32 + g*8 + e;
        float v0 = 0.f, v1 = 0.f;
        if (col == 0)     { v0 = w_sigma[u0];           v1 = w_sigma[u1]; }
        else if (col < 4) { v0 = W_rgb[u0*3 + (col-1)]; v1 = W_rgb[u1*3 + (col-1)]; }
        bf0[e] = (_Float16)v0; bf1[e] = (_Float16)v1;
    }

    // per-ray view-dependent rgb bias for BOTH rays of this wave, computed
    // up front (ray_dir is L1/L2-hot from the staging pass just above).
    float dwrA[2], dwgA[2], dwbA[2];
#pragma unroll
    for (int qq = 0; qq < 2; ++qq) {
        const int ray = blockIdx.x * RPB + wave*2 + qq;
        const float ddx = ray_dir[ray*3+0], ddy = ray_dir[ray*3+1], ddz = ray_dir[ray*3+2];
        dwrA[qq] = fmaf(ddx, W_dir[0], fmaf(ddy, W_dir[3], fmaf(ddz, W_dir[6], b_rgb[0])));
        dwgA[qq] = fmaf(ddx, W_dir[1], fmaf(ddy, W_dir[4], fmaf(ddz, W_dir[7], b_rgb[1])));
        dwbA[qq] = fmaf(ddx, W_dir[2], fmaf(ddy, W_dir[5], fmaf(ddz, W_dir[8], b_rgb[2])));
    }

    const f16x2 zero2 = mk2(0.f, 0.f);
    const f32x4 zacc  = {0.f, 0.f, 0.f, 0.f};

    const int sb = 4*lane;   // this lane's 4 samples in the epilogue

    // prefetch set for the epilogue globals (issued one q-iteration ahead;
    // the ~900-cycle HBM miss hides under the MFMA main loop / shfl chains)
    float4 dptP, dsvP; int4 vidP;
    {
        const size_t rb = (size_t)(blockIdx.x * RPB + wave*2) * NS + (size_t)sb;
        dptP = *(const float4*)(sampled_depth + rb);
        dsvP = *(const float4*)(sampled_dists + rb);
        vidP = *(const int4*)(sampled_idx + rb);
    }

#pragma unroll 1
    for (int q = 0; q < 2; ++q) {
        const int r   = wave*2 + q;
        const int ray = blockIdx.x * RPB + r;

        // lane's MLP coefficients: unit pairs g*4+d (chunk0), 16+g*4+d (chunk1)
        AB2 c0[4], c1[4];
#pragma unroll
        for (int d = 0; d < 4; ++d) {
            c0[d] = sAB[r][4*g + d];
            c1[d] = sAB[r][16 + 4*g + d];
        }

        f32x4 acc[16];
#pragma unroll
        for (int b = 0; b < 16; ++b) acc[b] = zacc;

        // main loop: 16 blocks of 16 samples; per block 16 VALU + 2 MFMA
#pragma unroll
        for (int b = 0; b < 16; ++b) {
            const f16x2 t2 = sDep[r][16*b + col];   // sample 16b+col, broadcast x4 groups
            AFrag a0, a1;
#pragma unroll
            for (int d = 0; d < 4; ++d) {
                a0.h[d] = __builtin_elementwise_max(
                    __builtin_elementwise_fma(c0[d].B, t2, c0[d].A), zero2);
                a1.h[d] = __builtin_elementwise_max(
                    __builtin_elementwise_fma(c1[d].B, t2, c1[d].A), zero2);
            }
            acc[b] = __builtin_amdgcn_mfma_f32_16x16x32_f16(a0.v, bf0, acc[b], 0, 0, 0);
            acc[b] = __builtin_amdgcn_mfma_f32_16x16x32_f16(a1.v, bf1, acc[b], 0, 0, 0);
        }

        // transpose D -> sample-major via wave-private LDS.
        // D layout: col = lane&15, row(sample-in-block) = 4*g + reg  (m89-verified)
        if (col < 4) {
#pragma unroll
            for (int b = 0; b < 16; ++b) {
                float4 v; v.x = acc[b][0]; v.y = acc[b][1]; v.z = acc[b][2]; v.w = acc[b][3];
                *(float4*)&sOut[wave][col][16*b + 4*g] = v;   // samples 16b+4g..+3
            }
        }

        // consume the prefetched globals for THIS q, then immediately issue
        // next q's loads so they fly under this epilogue's shfl chains.
        const float4 dpt = dptP;
        const float4 dsv = dsvP;
        const int4   vid = vidP;
        if (q == 0) {
            const size_t rbn = (size_t)(ray + 1) * NS + (size_t)sb;
            dptP = *(const float4*)(sampled_depth + rbn);
            dsvP = *(const float4*)(sampled_dists + rbn);
            vidP = *(const int4*)(sampled_idx + rbn);
        }

        // ---- epilogue: 64 lanes x 4 samples each ----
        const float4 sg  = *(const float4*)&sOut[wave][0][sb];
        const float4 cr4 = *(const float4*)&sOut[wave][1][sb];
        const float4 cg4 = *(const float4*)&sOut[wave][2][sb];
        const float4 cb4 = *(const float4*)&sOut[wave][3][sb];

        const float dwr = dwrA[q], dwg = dwgA[q], dwb = dwbA[q];

        const float sigA[4] = {sg.x,  sg.y,  sg.z,  sg.w};
        const float crA[4]  = {cr4.x, cr4.y, cr4.z, cr4.w};
        const float cgA[4]  = {cg4.x, cg4.y, cg4.z, cg4.w};
        const float cbA[4]  = {cb4.x, cb4.y, cb4.z, cb4.w};
        const float dptA[4] = {dpt.x, dpt.y, dpt.z, dpt.w};
        const float dsvA[4] = {dsv.x, dsv.y, dsv.z, dsv.w};
        const int   vidA[4] = {vid.x, vid.y, vid.z, vid.w};

        // free energy + thread-local inclusive scan
        float c[4]; float run = 0.f;
#pragma unroll
        for (int j = 0; j < 4; ++j) {
            float f = fmaxf(sigA[j], 0.f) * dsvA[j] * 7.0f;
            if (vidA[j] == -1) f = 0.f;
            run += f; c[j] = run;
        }

        // wave-wide (64) exclusive scan of per-thread totals
        float tot = run;
#pragma unroll
        for (int off = 1; off < 64; off <<= 1) {
            const float v = __shfl_up(tot, off, 64);
            if (lane >= off) tot += v;
        }
        const float base = tot - run;

        // telescoped probs: p[j] = exp(-(base+c[j-1])) - exp(-(base+c[j]))
        float Eprev = __expf(-base);
        float prob[4];
        float sS = 0.f, sD = 0.f, sR = 0.f, sG = 0.f, sB = 0.f;
#pragma unroll
        for (int j = 0; j < 4; ++j) {
            const float Ej = __expf(-(base + c[j]));
            const float p  = Eprev - Ej;
            Eprev = Ej;
            prob[j] = p;
            const float rr2 = __builtin_amdgcn_rcpf(1.f + __expf(-(crA[j] + dwr)));
            const float gg2 = __builtin_amdgcn_rcpf(1.f + __expf(-(cgA[j] + dwg)));
            const float bb2 = __builtin_amdgcn_rcpf(1.f + __expf(-(cbA[j] + dwb)));
            sS += p;
            sD = fmaf(dptA[j], p, sD);
            sR = fmaf(rr2, p, sR);
            sG = fmaf(gg2, p, sG);
            sB = fmaf(bb2, p, sB);
        }

        // wave reduction of the 5 sums
#pragma unroll
        for (int off = 32; off >= 1; off >>= 1) {
            sS += __shfl_xor(sS, off);
            sD += __shfl_xor(sD, off);
            sR += __shfl_xor(sR, off);
            sG += __shfl_xor(sG, off);
            sB += __shfl_xor(sB, off);
        }

        float* orow = out + (size_t)ray * (NS + 5);
#pragma unroll
        for (int j = 0; j < 4; ++j)
            orow[5 + sb + j] = prob[j];

        if (lane == 0) {
            orow[0] = sR;          // r
            orow[1] = sG;          // g
            orow[2] = sB;          // b
            orow[3] = sD;          // depth
            orow[4] = 1.f - sS;    // missed
        }
    }
}

extern "C" void kernel_launch(void* const* d_in, const int* in_sizes, int n_in,
                              void* d_out, int out_size, void* d_ws, size_t ws_size,
                              hipStream_t stream)
{
    vr_kernel<<<NRAYS / RPB, 256, 0, stream>>>(
        (const float*)d_in[0],   // ray_start
        (const float*)d_in[1],   // ray_dir
        (const float*)d_in[2],   // sampled_depth
        (const float*)d_in[3],   // sampled_dists
        (const int*)  d_in[4],   // sampled_idx
        (const float*)d_in[5],   // W1
        (const float*)d_in[6],   // b1
        (const float*)d_in[7],   // w_sigma
        (const float*)d_in[8],   // W_rgb
        (const float*)d_in[9],   // W_dir
        (const float*)d_in[10],  // b_rgb
        (float*)d_out);
}

// Round 3
// 100.826 us; speedup vs baseline: 1.0234x; 1.0234x over previous
//
#include <hip/hip_runtime.h>

#define NRAYS 8192
#define NS    256
#define HID   64
#define NPAIR 32     // hidden-unit pairs
#define RPB   8      // rays per block: 4 waves x 2 rays each

typedef _Float16 f16x2 __attribute__((ext_vector_type(2)));
typedef _Float16 f16x8 __attribute__((ext_vector_type(8)));
typedef float    f32x4 __attribute__((ext_vector_type(4)));

static __device__ __forceinline__ f16x2 mk2(float a, float b) {
    f16x2 v; v.x = (_Float16)a; v.y = (_Float16)b; return v;
}

struct __align__(8) AB2 { f16x2 A, B; };   // hv(h,t) = relu(A + t*B), 2 units packed
union AFrag { f16x8 v; f16x2 h[4]; };      // MFMA A-operand built from 4 pk results

__global__ __launch_bounds__(256, 4) void vr_kernel(
    const float* __restrict__ ray_start,
    const float* __restrict__ ray_dir,
    const float* __restrict__ sampled_depth,
    const float* __restrict__ sampled_dists,
    const int*   __restrict__ sampled_idx,
    const float* __restrict__ W1,
    const float* __restrict__ b1,
    const float* __restrict__ w_sigma,
    const float* __restrict__ W_rgb,
    const float* __restrict__ W_dir,
    const float* __restrict__ b_rgb,
    float* __restrict__ out)
{
    // All LDS regions are produced and consumed by the SAME wave (wave w owns
    // rays 2w and 2w+1; staging threads t have t>>5 == 2w or 2w+1). DS ops from
    // one wave execute in order -> no __syncthreads anywhere.
    __shared__ AB2   sAB[RPB][NPAIR];                 // 2 KB
    __shared__ f16x2 sDep[RPB][NS];                   // 8 KB   (t,t) f16 pairs
    __shared__ __align__(16) float sOut[4][4][264];   // 16.9 KB, per-wave transpose buf (pad 264)

    const int t = threadIdx.x;

    {   // stage sAB: 256 threads = 8 rays x 32 pairs
        const int rr  = t >> 5;
        const int k   = t & (NPAIR - 1);
        const int ray = blockIdx.x * RPB + rr;
        const float ox = ray_start[ray*3+0], oy = ray_start[ray*3+1], oz = ray_start[ray*3+2];
        const float dx = ray_dir[ray*3+0],  dy = ray_dir[ray*3+1],  dz = ray_dir[ray*3+2];
        const int h0 = 2*k, h1 = 2*k + 1;
        const float u0 = W1[h0], u1 = W1[HID + h0], u2 = W1[2*HID + h0];
        const float v0 = W1[h1], v1 = W1[HID + h1], v2 = W1[2*HID + h1];
        const float A0 = fmaf(u0, ox, fmaf(u1, oy, fmaf(u2, oz, b1[h0])));
        const float B0 = fmaf(u0, dx, fmaf(u1, dy, u2 * dz));
        const float A1 = fmaf(v0, ox, fmaf(v1, oy, fmaf(v2, oz, b1[h1])));
        const float B1 = fmaf(v0, dx, fmaf(v1, dy, v2 * dz));
        AB2 e; e.A = mk2(A0, A1); e.B = mk2(B0, B1);
        sAB[rr][k] = e;
    }
    {   // stage sDep: depth as broadcast f16 pairs, 8 samples/thread
        const int rr  = t >> 5;
        const int i   = t & 31;
        const int ray = blockIdx.x * RPB + rr;
        const size_t base = (size_t)ray * NS + (size_t)i * 8;
        const float4 d0 = ((const float4*)(sampled_depth + base))[0];
        const float4 d1 = ((const float4*)(sampled_depth + base))[1];
        f16x2* dst = &sDep[rr][i*8];
        dst[0] = mk2(d0.x, d0.x); dst[1] = mk2(d0.y, d0.y);
        dst[2] = mk2(d0.z, d0.z); dst[3] = mk2(d0.w, d0.w);
        dst[4] = mk2(d1.x, d1.x); dst[5] = mk2(d1.y, d1.y);
        dst[6] = mk2(d1.z, d1.z); dst[7] = mk2(d1.w, d1.w);
    }

    const int lane = t & 63;
    const int wave = t >> 6;
    const int col  = lane & 15;   // A-row (sample-in-block) == B/D col (output)
    const int g    = lane >> 4;   // k-chunk group

    // B fragments, pinned in VGPRs for the whole kernel.
    // B[k][col]: col0 = w_sigma, col1..3 = W_rgb[:,col-1], col>=4 zero.
    // lane holds k = g*8+e (bf0) and 32+g*8+e (bf1).
    f16x8 bf0, bf1;
#pragma unroll
    for (int e = 0; e < 8; ++e) {
        const int u0 = g*8 + e, u1 = 32 + g*8 + e;
        float v0 = 0.f, v1 = 0.f;
        if (col == 0)     { v0 = w_sigma[u0];           v1 = w_sigma[u1]; }
        else if (col < 4) { v0 = W_rgb[u0*3 + (col-1)]; v1 = W_rgb[u1*3 + (col-1)]; }
        bf0[e] = (_Float16)v0; bf1[e] = (_Float16)v1;
    }

    const f16x2 zero2 = mk2(0.f, 0.f);
    const f32x4 zacc  = {0.f, 0.f, 0.f, 0.f};
    const int sb = 4*lane;   // this lane's 4 samples in the epilogue

#pragma unroll 1
    for (int q = 0; q < 2; ++q) {
        const int r   = wave*2 + q;
        const int ray = blockIdx.x * RPB + r;

        // lane's MLP coefficients: unit pairs g*4+d (chunk0), 16+g*4+d (chunk1)
        AB2 c0[4], c1[4];
#pragma unroll
        for (int d = 0; d < 4; ++d) {
            c0[d] = sAB[r][4*g + d];
            c1[d] = sAB[r][16 + 4*g + d];
        }

        // per-ray view-dependent rgb bias (L1-hot loads; issued early so the
        // latency hides under pass 0)
        const float ddx = ray_dir[ray*3+0], ddy = ray_dir[ray*3+1], ddz = ray_dir[ray*3+2];
        const float dwr = fmaf(ddx, W_dir[0], fmaf(ddy, W_dir[3], fmaf(ddz, W_dir[6], b_rgb[0])));
        const float dwg = fmaf(ddx, W_dir[1], fmaf(ddy, W_dir[4], fmaf(ddz, W_dir[7], b_rgb[1])));
        const float dwb = fmaf(ddx, W_dir[2], fmaf(ddy, W_dir[5], fmaf(ddz, W_dir[8], b_rgb[2])));

        // epilogue globals for this ray: declared here, issued after pass 0 so
        // pass 1's MFMA work covers their latency.
        float4 dpt, dsv; int4 vid;

        // ---- main loop in TWO passes of 8 sample-blocks: acc[8] = 32 VGPRs
        // (halved live accumulator range vs acc[16]; keeps peak pressure well
        //  under the 128-VGPR cap imposed by __launch_bounds__(256,4)) ----
#pragma unroll
        for (int p = 0; p < 2; ++p) {
            f32x4 acc[8];
#pragma unroll
            for (int b = 0; b < 8; ++b) acc[b] = zacc;

#pragma unroll
            for (int b = 0; b < 8; ++b) {
                const int bb = 8*p + b;
                const f16x2 t2 = sDep[r][16*bb + col];  // sample 16bb+col
                AFrag a0, a1;
#pragma unroll
                for (int d = 0; d < 4; ++d) {
                    a0.h[d] = __builtin_elementwise_max(
                        __builtin_elementwise_fma(c0[d].B, t2, c0[d].A), zero2);
                    a1.h[d] = __builtin_elementwise_max(
                        __builtin_elementwise_fma(c1[d].B, t2, c1[d].A), zero2);
                }
                acc[b] = __builtin_amdgcn_mfma_f32_16x16x32_f16(a0.v, bf0, acc[b], 0, 0, 0);
                acc[b] = __builtin_amdgcn_mfma_f32_16x16x32_f16(a1.v, bf1, acc[b], 0, 0, 0);
            }

            // transpose D -> sample-major via wave-private LDS.
            // D layout: col = lane&15, row(sample-in-block) = 4*g + reg  (m89-verified)
            if (col < 4) {
#pragma unroll
                for (int b = 0; b < 8; ++b) {
                    const int bb = 8*p + b;
                    float4 v; v.x = acc[b][0]; v.y = acc[b][1]; v.z = acc[b][2]; v.w = acc[b][3];
                    *(float4*)&sOut[wave][col][16*bb + 4*g] = v;  // samples 16bb+4g..+3
                }
            }

            if (p == 0) {   // issue epilogue loads; pass 1 hides their latency
                const size_t rb = (size_t)ray * NS + (size_t)sb;
                dpt = *(const float4*)(sampled_depth + rb);
                dsv = *(const float4*)(sampled_dists + rb);
                vid = *(const int4*)(sampled_idx + rb);
            }
        }

        // ---- epilogue: 64 lanes x 4 samples each ----
        const float4 sg  = *(const float4*)&sOut[wave][0][sb];
        const float4 cr4 = *(const float4*)&sOut[wave][1][sb];
        const float4 cg4 = *(const float4*)&sOut[wave][2][sb];
        const float4 cb4 = *(const float4*)&sOut[wave][3][sb];

        const float sigA[4] = {sg.x,  sg.y,  sg.z,  sg.w};
        const float crA[4]  = {cr4.x, cr4.y, cr4.z, cr4.w};
        const float cgA[4]  = {cg4.x, cg4.y, cg4.z, cg4.w};
        const float cbA[4]  = {cb4.x, cb4.y, cb4.z, cb4.w};
        const float dptA[4] = {dpt.x, dpt.y, dpt.z, dpt.w};
        const float dsvA[4] = {dsv.x, dsv.y, dsv.z, dsv.w};
        const int   vidA[4] = {vid.x, vid.y, vid.z, vid.w};

        // free energy + thread-local inclusive scan
        float c[4]; float run = 0.f;
#pragma unroll
        for (int j = 0; j < 4; ++j) {
            float f = fmaxf(sigA[j], 0.f) * dsvA[j] * 7.0f;
            if (vidA[j] == -1) f = 0.f;
            run += f; c[j] = run;
        }

        // wave-wide (64) exclusive scan of per-thread totals
        float tot = run;
#pragma unroll
        for (int off = 1; off < 64; off <<= 1) {
            const float v = __shfl_up(tot, off, 64);
            if (lane >= off) tot += v;
        }
        const float base = tot - run;

        // telescoped probs: p[j] = exp(-(base+c[j-1])) - exp(-(base+c[j]))
        float Eprev = __expf(-base);
        float prob[4];
        float sS = 0.f, sD = 0.f, sR = 0.f, sG = 0.f, sB = 0.f;
#pragma unroll
        for (int j = 0; j < 4; ++j) {
            const float Ej = __expf(-(base + c[j]));
            const float p  = Eprev - Ej;
            Eprev = Ej;
            prob[j] = p;
            const float rr2 = __builtin_amdgcn_rcpf(1.f + __expf(-(crA[j] + dwr)));
            const float gg2 = __builtin_amdgcn_rcpf(1.f + __expf(-(cgA[j] + dwg)));
            const float bb2 = __builtin_amdgcn_rcpf(1.f + __expf(-(cbA[j] + dwb)));
            sS += p;
            sD = fmaf(dptA[j], p, sD);
            sR = fmaf(rr2, p, sR);
            sG = fmaf(gg2, p, sG);
            sB = fmaf(bb2, p, sB);
        }

        // wave reduction of the 5 sums
#pragma unroll
        for (int off = 32; off >= 1; off >>= 1) {
            sS += __shfl_xor(sS, off);
            sD += __shfl_xor(sD, off);
            sR += __shfl_xor(sR, off);
            sG += __shfl_xor(sG, off);
            sB += __shfl_xor(sB, off);
        }

        float* orow = out + (size_t)ray * (NS + 5);
#pragma unroll
        for (int j = 0; j < 4; ++j)
            orow[5 + sb + j] = prob[j];

        if (lane == 0) {
            orow[0] = sR;          // r
            orow[1] = sG;          // g
            orow[2] = sB;          // b
            orow[3] = sD;          // depth
            orow[4] = 1.f - sS;    // missed
        }
    }
}

extern "C" void kernel_launch(void* const* d_in, const int* in_sizes, int n_in,
                              void* d_out, int out_size, void* d_ws, size_t ws_size,
                              hipStream_t stream)
{
    vr_kernel<<<NRAYS / RPB, 256, 0, stream>>>(
        (const float*)d_in[0],   // ray_start
        (const float*)d_in[1],   // ray_dir
        (const float*)d_in[2],   // sampled_depth
        (const float*)d_in[3],   // sampled_dists
        (const int*)  d_in[4],   // sampled_idx
        (const float*)d_in[5],   // W1
        (const float*)d_in[6],   // b1
        (const float*)d_in[7],   // w_sigma
        (const float*)d_in[8],   // W_rgb
        (const float*)d_in[9],   // W_dir
        (const float*)d_in[10],  // b_rgb
        (float*)d_out);
}

// Round 4
// 100.712 us; speedup vs baseline: 1.0246x; 1.0011x over previous
//
#include <hip/hip_runtime.h>

#define NRAYS 8192
#define NS    256
#define HID   64
#define NPAIR 32     // hidden-unit pairs
#define RPB   8      // rays per block: 4 waves x 2 rays each

typedef _Float16 f16x2 __attribute__((ext_vector_type(2)));
typedef _Float16 f16x8 __attribute__((ext_vector_type(8)));
typedef float    f32x4 __attribute__((ext_vector_type(4)));

static __device__ __forceinline__ f16x2 mk2(float a, float b) {
    f16x2 v; v.x = (_Float16)a; v.y = (_Float16)b; return v;
}

struct __align__(8) AB2 { f16x2 A, B; };   // hv(h,t) = relu(A + t*B), 2 units packed
union AFrag { f16x8 v; f16x2 h[4]; };      // MFMA A-operand built from 4 pk results

__global__ __launch_bounds__(256, 4) void vr_kernel(
    const float* __restrict__ ray_start,
    const float* __restrict__ ray_dir,
    const float* __restrict__ sampled_depth,
    const float* __restrict__ sampled_dists,
    const int*   __restrict__ sampled_idx,
    const float* __restrict__ W1,
    const float* __restrict__ b1,
    const float* __restrict__ w_sigma,
    const float* __restrict__ W_rgb,
    const float* __restrict__ W_dir,
    const float* __restrict__ b_rgb,
    float* __restrict__ out)
{
    // All LDS regions are produced and consumed by the SAME wave (wave w owns
    // rays 2w and 2w+1). DS ops from one wave execute in order -> no barrier.
    __shared__ AB2 sAB[RPB][NPAIR];                       // 2 KB
    __shared__ __align__(16) _Float16 sDepF[RPB][NS];     // 4 KB   scalar f16 depth
    __shared__ __align__(16) float sOut[4][2][4][264];    // 33 KB  [wave][ray][chan][sample+pad]
    // total 39.9 KB -> 4 blocks/CU retained

    const int t = threadIdx.x;

    {   // stage sAB: 256 threads = 8 rays x 32 pairs
        const int rr  = t >> 5;
        const int k   = t & (NPAIR - 1);
        const int ray = blockIdx.x * RPB + rr;
        const float ox = ray_start[ray*3+0], oy = ray_start[ray*3+1], oz = ray_start[ray*3+2];
        const float dx = ray_dir[ray*3+0],  dy = ray_dir[ray*3+1],  dz = ray_dir[ray*3+2];
        const int h0 = 2*k, h1 = 2*k + 1;
        const float u0 = W1[h0], u1 = W1[HID + h0], u2 = W1[2*HID + h0];
        const float v0 = W1[h1], v1 = W1[HID + h1], v2 = W1[2*HID + h1];
        const float A0 = fmaf(u0, ox, fmaf(u1, oy, fmaf(u2, oz, b1[h0])));
        const float B0 = fmaf(u0, dx, fmaf(u1, dy, u2 * dz));
        const float A1 = fmaf(v0, ox, fmaf(v1, oy, fmaf(v2, oz, b1[h1])));
        const float B1 = fmaf(v0, dx, fmaf(v1, dy, v2 * dz));
        AB2 e; e.A = mk2(A0, A1); e.B = mk2(B0, B1);
        sAB[rr][k] = e;
    }
    {   // stage sDepF: scalar f16 depths, 8 samples/thread, one b128 store
        const int rr  = t >> 5;
        const int i   = t & 31;
        const int ray = blockIdx.x * RPB + rr;
        const size_t base = (size_t)ray * NS + (size_t)i * 8;
        const float4 d0 = ((const float4*)(sampled_depth + base))[0];
        const float4 d1 = ((const float4*)(sampled_depth + base))[1];
        f16x8 pk;
        pk[0] = (_Float16)d0.x; pk[1] = (_Float16)d0.y;
        pk[2] = (_Float16)d0.z; pk[3] = (_Float16)d0.w;
        pk[4] = (_Float16)d1.x; pk[5] = (_Float16)d1.y;
        pk[6] = (_Float16)d1.z; pk[7] = (_Float16)d1.w;
        *(f16x8*)&sDepF[rr][i*8] = pk;
    }

    const int lane = t & 63;
    const int wave = t >> 6;
    const int col  = lane & 15;   // A-row (sample-in-block) == B/D col (output)
    const int g    = lane >> 4;   // k-chunk group

    // epilogue geometry: half-wave per ray, 8 samples/lane
    const int hl   = lane & 31;
    const int rq   = lane >> 5;
    const int eray = blockIdx.x * RPB + wave*2 + rq;

    // B fragments, pinned in VGPRs for the whole kernel.
    f16x8 bf0, bf1;
#pragma unroll
    for (int e = 0; e < 8; ++e) {
        const int u0 = g*8 + e, u1 = 32 + g*8 + e;
        float v0 = 0.f, v1 = 0.f;
        if (col == 0)     { v0 = w_sigma[u0];           v1 = w_sigma[u1]; }
        else if (col < 4) { v0 = W_rgb[u0*3 + (col-1)]; v1 = W_rgb[u1*3 + (col-1)]; }
        bf0[e] = (_Float16)v0; bf1[e] = (_Float16)v1;
    }

    // per-lane view-dependent rgb bias for this lane's epilogue ray (L1-hot)
    float dwr, dwg, dwb;
    {
        const float ddx = ray_dir[eray*3+0], ddy = ray_dir[eray*3+1], ddz = ray_dir[eray*3+2];
        dwr = fmaf(ddx, W_dir[0], fmaf(ddy, W_dir[3], fmaf(ddz, W_dir[6], b_rgb[0])));
        dwg = fmaf(ddx, W_dir[1], fmaf(ddy, W_dir[4], fmaf(ddz, W_dir[7], b_rgb[1])));
        dwb = fmaf(ddx, W_dir[2], fmaf(ddy, W_dir[5], fmaf(ddz, W_dir[8], b_rgb[2])));
    }

    const f16x2 zero2 = mk2(0.f, 0.f);
    const f32x4 zacc  = {0.f, 0.f, 0.f, 0.f};

    // epilogue globals (8 samples/lane), issued between main-q1's two passes
    float4 dptE0, dptE1, dsvE0, dsvE1; int4 vidE0, vidE1;

    auto run_main = [&](int q, bool pf) {
        const int r = wave*2 + q;

        AB2 c0[4], c1[4];
#pragma unroll
        for (int d = 0; d < 4; ++d) {
            c0[d] = sAB[r][4*g + d];
            c1[d] = sAB[r][16 + 4*g + d];
        }

        const unsigned short* sd = (const unsigned short*)sDepF[r];

#pragma unroll
        for (int p = 0; p < 2; ++p) {
            f32x4 acc[8];
#pragma unroll
            for (int b = 0; b < 8; ++b) acc[b] = zacc;

#pragma unroll
            for (int b = 0; b < 8; ++b) {
                const int bb = 8*p + b;
                const unsigned int raw = sd[16*bb + col];          // ds_read_u16
                const unsigned int bits = (raw << 16) | raw;       // v_lshl_or_b32
                const f16x2 t2 = __builtin_bit_cast(f16x2, bits);  // (t,t)
                AFrag a0, a1;
#pragma unroll
                for (int d = 0; d < 4; ++d) {
                    a0.h[d] = __builtin_elementwise_max(
                        __builtin_elementwise_fma(c0[d].B, t2, c0[d].A), zero2);
                    a1.h[d] = __builtin_elementwise_max(
                        __builtin_elementwise_fma(c1[d].B, t2, c1[d].A), zero2);
                }
                acc[b] = __builtin_amdgcn_mfma_f32_16x16x32_f16(a0.v, bf0, acc[b], 0, 0, 0);
                acc[b] = __builtin_amdgcn_mfma_f32_16x16x32_f16(a1.v, bf1, acc[b], 0, 0, 0);
            }

            // transpose D -> sample-major. D layout: col=lane&15,
            // row(sample-in-block) = 4*g + reg  (m89-verified)
            if (col < 4) {
#pragma unroll
                for (int b = 0; b < 8; ++b) {
                    const int bb = 8*p + b;
                    float4 v; v.x = acc[b][0]; v.y = acc[b][1]; v.z = acc[b][2]; v.w = acc[b][3];
                    *(float4*)&sOut[wave][q][col][16*bb + 4*g] = v;
                }
            }

            if (pf && p == 0) {   // issue epilogue loads; pass 1 hides latency
                const size_t erb = (size_t)eray * NS + (size_t)hl * 8;
                dptE0 = ((const float4*)(sampled_depth + erb))[0];
                dptE1 = ((const float4*)(sampled_depth + erb))[1];
                dsvE0 = ((const float4*)(sampled_dists + erb))[0];
                dsvE1 = ((const float4*)(sampled_dists + erb))[1];
                vidE0 = ((const int4*)(sampled_idx + erb))[0];
                vidE1 = ((const int4*)(sampled_idx + erb))[1];
            }
        }
    };

    run_main(0, false);
    run_main(1, true);

    // ---- single epilogue: half-wave (32 lanes) per ray, 8 samples/lane ----
    const int sb = 8*hl;
    const float4 sg0 = *(const float4*)&sOut[wave][rq][0][sb];
    const float4 sg1 = *(const float4*)&sOut[wave][rq][0][sb+4];
    const float4 cr0 = *(const float4*)&sOut[wave][rq][1][sb];
    const float4 cr1 = *(const float4*)&sOut[wave][rq][1][sb+4];
    const float4 cg0 = *(const float4*)&sOut[wave][rq][2][sb];
    const float4 cg1 = *(const float4*)&sOut[wave][rq][2][sb+4];
    const float4 cb0 = *(const float4*)&sOut[wave][rq][3][sb];
    const float4 cb1 = *(const float4*)&sOut[wave][rq][3][sb+4];

    const float sigA[8] = {sg0.x, sg0.y, sg0.z, sg0.w, sg1.x, sg1.y, sg1.z, sg1.w};
    const float crA[8]  = {cr0.x, cr0.y, cr0.z, cr0.w, cr1.x, cr1.y, cr1.z, cr1.w};
    const float cgA[8]  = {cg0.x, cg0.y, cg0.z, cg0.w, cg1.x, cg1.y, cg1.z, cg1.w};
    const float cbA[8]  = {cb0.x, cb0.y, cb0.z, cb0.w, cb1.x, cb1.y, cb1.z, cb1.w};
    const float dptA[8] = {dptE0.x, dptE0.y, dptE0.z, dptE0.w, dptE1.x, dptE1.y, dptE1.z, dptE1.w};
    const float dsvA[8] = {dsvE0.x, dsvE0.y, dsvE0.z, dsvE0.w, dsvE1.x, dsvE1.y, dsvE1.z, dsvE1.w};
    const int   vidA[8] = {vidE0.x, vidE0.y, vidE0.z, vidE0.w, vidE1.x, vidE1.y, vidE1.z, vidE1.w};

    // free energy + thread-local inclusive scan
    float c[8]; float run = 0.f;
#pragma unroll
    for (int j = 0; j < 8; ++j) {
        float f = fmaxf(sigA[j], 0.f) * dsvA[j] * 7.0f;
        if (vidA[j] == -1) f = 0.f;
        run += f; c[j] = run;
    }

    // half-wave (width 32) exclusive scan of per-thread totals
    float tot = run;
#pragma unroll
    for (int off = 1; off < 32; off <<= 1) {
        const float v = __shfl_up(tot, off, 32);
        if (hl >= off) tot += v;
    }
    const float base = tot - run;

    // telescoped probs: p[j] = exp(-(base+c[j-1])) - exp(-(base+c[j]))
    float Eprev = __expf(-base);
    float prob[8];
    float sS = 0.f, sD = 0.f, sR = 0.f, sG = 0.f, sB = 0.f;
#pragma unroll
    for (int j = 0; j < 8; ++j) {
        const float Ej = __expf(-(base + c[j]));
        const float p  = Eprev - Ej;
        Eprev = Ej;
        prob[j] = p;
        const float rr2 = __builtin_amdgcn_rcpf(1.f + __expf(-(crA[j] + dwr)));
        const float gg2 = __builtin_amdgcn_rcpf(1.f + __expf(-(cgA[j] + dwg)));
        const float bb2 = __builtin_amdgcn_rcpf(1.f + __expf(-(cbA[j] + dwb)));
        sS += p;
        sD = fmaf(dptA[j], p, sD);
        sR = fmaf(rr2, p, sR);
        sG = fmaf(gg2, p, sG);
        sB = fmaf(bb2, p, sB);
    }

    // half-wave reduction of the 5 sums (both rays in parallel)
#pragma unroll
    for (int off = 16; off >= 1; off >>= 1) {
        sS += __shfl_xor(sS, off, 32);
        sD += __shfl_xor(sD, off, 32);
        sR += __shfl_xor(sR, off, 32);
        sG += __shfl_xor(sG, off, 32);
        sB += __shfl_xor(sB, off, 32);
    }

    float* orow = out + (size_t)eray * (NS + 5);
#pragma unroll
    for (int j = 0; j < 8; ++j)
        orow[5 + sb + j] = prob[j];

    if (hl == 0) {
        orow[0] = sR;          // r
        orow[1] = sG;          // g
        orow[2] = sB;          // b
        orow[3] = sD;          // depth
        orow[4] = 1.f - sS;    // missed
    }
}

extern "C" void kernel_launch(void* const* d_in, const int* in_sizes, int n_in,
                              void* d_out, int out_size, void* d_ws, size_t ws_size,
                              hipStream_t stream)
{
    vr_kernel<<<NRAYS / RPB, 256, 0, stream>>>(
        (const float*)d_in[0],   // ray_start
        (const float*)d_in[1],   // ray_dir
        (const float*)d_in[2],   // sampled_depth
        (const float*)d_in[3],   // sampled_dists
        (const int*)  d_in[4],   // sampled_idx
        (const float*)d_in[5],   // W1
        (const float*)d_in[6],   // b1
        (const float*)d_in[7],   // w_sigma
        (const float*)d_in[8],   // W_rgb
        (const float*)d_in[9],   // W_dir
        (const float*)d_in[10],  // b_rgb
        (float*)d_out);
}